// Round 4
// baseline (561.033 us; speedup 1.0000x reference)
//
#include <hip/hip_runtime.h>

// DynamicVoxelEncoder: range filter + quantize + scatter-mean per voxel.
// points: [B=4, N=300000, 5] float32 (x,y,z,f0,f1)
// out (flat float32): voxels [B,NV,5] | counts [B,NV] | shape [3]
// NV = 540*540*8 = 2,332,800

#define NX_ 540
#define NY_ 540
#define NZ_ 8
#define NV_ (NX_ * NY_ * NZ_)
#define B_ 4
#define N_ 300000

__global__ __launch_bounds__(256) void voxel_scatter(
    const float* __restrict__ pts,   // [B*N, 5]
    float* __restrict__ sums,        // [B*NV, 5]
    float* __restrict__ cnts)        // [B*NV]
{
    int g = blockIdx.x * blockDim.x + threadIdx.x;
    if (g >= B_ * N_) return;

    const float* p = pts + (size_t)g * 5;
    float x  = p[0];
    float y  = p[1];
    float z  = p[2];
    float f0 = p[3];
    float f1 = p[4];

    // range filter — inclusive both ends (compare decisions are precision-exact)
    bool keep = (x >= -54.0f) & (x <= 54.0f) &
                (y >= -54.0f) & (y <= 54.0f) &
                (z >= -5.0f)  & (z <= 3.0f);
    if (!keep) return;

    // Quantize: XLA canonicalizes (x - lo)/vox into (x - lo) * reciprocal(vox),
    // and reciprocal(0.2f) rounds to exactly 5.0f. So the reference's effective
    // f32 math is floor((x+54)*5). [R1 f32-divide, R2 f64-exact, R3 f64/f32vox
    // each left ~1 boundary point misassigned → absmax ~52.]
    float qx = (x + 54.0f) * 5.0f;
    float qy = (y + 54.0f) * 5.0f;
    float qz = (z + 5.0f);           // vox_z = 1.0, reciprocal exact
    int cx = (int)floorf(qx);
    int cy = (int)floorf(qy);
    int cz = (int)floorf(qz);
    cx = min(max(cx, 0), NX_ - 1);
    cy = min(max(cy, 0), NY_ - 1);
    cz = min(max(cz, 0), NZ_ - 1);

    int lin = (cz * NY_ + cy) * NX_ + cx;
    int b = g / N_;
    size_t vox = (size_t)b * NV_ + (size_t)lin;
    size_t base = vox * 5;

    atomicAdd(&sums[base + 0], x);
    atomicAdd(&sums[base + 1], y);
    atomicAdd(&sums[base + 2], z);
    atomicAdd(&sums[base + 3], f0);
    atomicAdd(&sums[base + 4], f1);
    atomicAdd(&cnts[vox], 1.0f);
}

__global__ __launch_bounds__(256) void voxel_finalize(
    float* __restrict__ sums,        // [B*NV, 5] in-place sums -> means
    const float* __restrict__ cnts,  // [B*NV]
    float* __restrict__ shape_out)   // [3]
{
    size_t idx = (size_t)blockIdx.x * blockDim.x + threadIdx.x;
    if (idx == 0) {
        shape_out[0] = 540.0f;
        shape_out[1] = 540.0f;
        shape_out[2] = 8.0f;
    }
    if (idx >= (size_t)B_ * NV_) return;

    float c = cnts[idx];
    if (c > 0.0f) {
        size_t base = idx * 5;
        // reference: sums / max(cnts, 1) — plain division
        sums[base + 0] /= c;
        sums[base + 1] /= c;
        sums[base + 2] /= c;
        sums[base + 3] /= c;
        sums[base + 4] /= c;
    }
    // c == 0: memset already left zeros, matching 0/1 = 0
}

extern "C" void kernel_launch(void* const* d_in, const int* in_sizes, int n_in,
                              void* d_out, int out_size, void* d_ws, size_t ws_size,
                              hipStream_t stream) {
    const float* points = (const float*)d_in[0];
    float* out = (float*)d_out;

    float* sums = out;                              // [B*NV*5]
    float* cnts = out + (size_t)B_ * NV_ * 5;       // [B*NV]
    float* shape_out = cnts + (size_t)B_ * NV_;     // [3]

    // d_out is poisoned to 0xAA before every timed launch — zero it.
    hipMemsetAsync(d_out, 0, (size_t)out_size * sizeof(float), stream);

    {
        int total = B_ * N_;
        int block = 256;
        int grid = (total + block - 1) / block;
        voxel_scatter<<<grid, block, 0, stream>>>(points, sums, cnts);
    }
    {
        size_t total = (size_t)B_ * NV_;
        int block = 256;
        int grid = (int)((total + block - 1) / block);
        voxel_finalize<<<grid, block, 0, stream>>>(sums, cnts, shape_out);
    }
}

// Round 5
// 329.223 us; speedup vs baseline: 1.7041x; 1.7041x over previous
//
#include <hip/hip_runtime.h>

// DynamicVoxelEncoder: range filter + quantize + scatter-mean per voxel.
// points: [B=4, N=300000, 5] float32 (x,y,z,f0,f1)
// out (flat float32): voxels [B,NV,5] | counts [B,NV] | shape [3]
//
// Strategy (R5): per-voxel linked lists.
//  - build: 1 atomicExch per kept point (vs 6 atomicAdds in R4), nodes written
//    coalesced at node==point index.
//  - output: 1 thread per voxel walks its chain, writes means+count exactly
//    once, fully coalesced -> no 187 MB memset, no scattered RMW finalize.

#define NX_ 540
#define NY_ 540
#define NZ_ 8
#define NV_ (NX_ * NY_ * NZ_)
#define B_ 4
#define N_ 300000
#define BN_ (B_ * N_)
#define NVB_ (B_ * NV_)

// ---------------- linked-list path ----------------

// node layout: 8 floats (32B, line-aligned): {x, y, z, f0, f1, next_as_int, pad, pad}
// written as float4 @0 and float2 @16.

__global__ __launch_bounds__(256) void voxel_build(
    const float* __restrict__ pts,   // [BN_, 5]
    int* __restrict__ head,          // [NVB_], pre-set to -1
    float* __restrict__ nodes)       // [BN_ * 8]
{
    int g = blockIdx.x * blockDim.x + threadIdx.x;
    if (g >= BN_) return;

    const float* p = pts + (size_t)g * 5;
    float x  = p[0];
    float y  = p[1];
    float z  = p[2];
    float f0 = p[3];
    float f1 = p[4];

    bool keep = (x >= -54.0f) & (x <= 54.0f) &
                (y >= -54.0f) & (y <= 54.0f) &
                (z >= -5.0f)  & (z <= 3.0f);
    if (!keep) return;

    // XLA-canonical quantization: (x - lo) * reciprocal(vox), rcp(0.2f)==5.0f
    int cx = (int)floorf((x + 54.0f) * 5.0f);
    int cy = (int)floorf((y + 54.0f) * 5.0f);
    int cz = (int)floorf(z + 5.0f);
    cx = min(max(cx, 0), NX_ - 1);
    cy = min(max(cy, 0), NY_ - 1);
    cz = min(max(cz, 0), NZ_ - 1);

    int lin = (cz * NY_ + cy) * NX_ + cx;
    int b = g / N_;
    int vox = b * NV_ + lin;

    float* nb = nodes + (size_t)g * 8;
    *(float4*)nb = make_float4(x, y, z, f0);

    int old = atomicExch(&head[vox], g);   // device-scope, returns previous head

    float2 tail;
    tail.x = f1;
    tail.y = __int_as_float(old);
    *(float2*)(nb + 4) = tail;
}

__global__ __launch_bounds__(256) void voxel_output(
    const int* __restrict__ head,    // [NVB_]
    const float* __restrict__ nodes, // [BN_ * 8]
    float* __restrict__ means,       // [NVB_, 5]
    float* __restrict__ cnts,        // [NVB_]
    float* __restrict__ shape_out)   // [3]
{
    int v = blockIdx.x * blockDim.x + threadIdx.x;
    if (v == 0) {
        shape_out[0] = 540.0f;
        shape_out[1] = 540.0f;
        shape_out[2] = 8.0f;
    }
    if (v >= NVB_) return;

    int i = head[v];
    float s0 = 0.f, s1 = 0.f, s2 = 0.f, s3 = 0.f, s4 = 0.f;
    int c = 0;
    while (i >= 0) {
        const float* nb = nodes + (size_t)i * 8;
        float4 a = *(const float4*)nb;
        float2 t = *(const float2*)(nb + 4);
        s0 += a.x; s1 += a.y; s2 += a.z; s3 += a.w; s4 += t.x;
        c++;
        i = __float_as_int(t.y);
    }

    float d = (float)max(c, 1);   // sums / max(cnt, 1)
    size_t mb = (size_t)v * 5;
    means[mb + 0] = s0 / d;
    means[mb + 1] = s1 / d;
    means[mb + 2] = s2 / d;
    means[mb + 3] = s3 / d;
    means[mb + 4] = s4 / d;
    cnts[v] = (float)c;
}

// ---------------- fallback path (R4, known-good) ----------------

__global__ __launch_bounds__(256) void voxel_scatter(
    const float* __restrict__ pts,
    float* __restrict__ sums,
    float* __restrict__ cnts)
{
    int g = blockIdx.x * blockDim.x + threadIdx.x;
    if (g >= BN_) return;
    const float* p = pts + (size_t)g * 5;
    float x = p[0], y = p[1], z = p[2], f0 = p[3], f1 = p[4];
    bool keep = (x >= -54.0f) & (x <= 54.0f) &
                (y >= -54.0f) & (y <= 54.0f) &
                (z >= -5.0f)  & (z <= 3.0f);
    if (!keep) return;
    int cx = (int)floorf((x + 54.0f) * 5.0f);
    int cy = (int)floorf((y + 54.0f) * 5.0f);
    int cz = (int)floorf(z + 5.0f);
    cx = min(max(cx, 0), NX_ - 1);
    cy = min(max(cy, 0), NY_ - 1);
    cz = min(max(cz, 0), NZ_ - 1);
    int lin = (cz * NY_ + cy) * NX_ + cx;
    int b = g / N_;
    size_t vox = (size_t)b * NV_ + (size_t)lin;
    size_t base = vox * 5;
    atomicAdd(&sums[base + 0], x);
    atomicAdd(&sums[base + 1], y);
    atomicAdd(&sums[base + 2], z);
    atomicAdd(&sums[base + 3], f0);
    atomicAdd(&sums[base + 4], f1);
    atomicAdd(&cnts[vox], 1.0f);
}

__global__ __launch_bounds__(256) void voxel_finalize(
    float* __restrict__ sums,
    const float* __restrict__ cnts,
    float* __restrict__ shape_out)
{
    size_t idx = (size_t)blockIdx.x * blockDim.x + threadIdx.x;
    if (idx == 0) {
        shape_out[0] = 540.0f;
        shape_out[1] = 540.0f;
        shape_out[2] = 8.0f;
    }
    if (idx >= (size_t)NVB_) return;
    float c = cnts[idx];
    if (c > 0.0f) {
        size_t base = idx * 5;
        sums[base + 0] /= c;
        sums[base + 1] /= c;
        sums[base + 2] /= c;
        sums[base + 3] /= c;
        sums[base + 4] /= c;
    }
}

// ---------------- launch ----------------

extern "C" void kernel_launch(void* const* d_in, const int* in_sizes, int n_in,
                              void* d_out, int out_size, void* d_ws, size_t ws_size,
                              hipStream_t stream) {
    const float* points = (const float*)d_in[0];
    float* out = (float*)d_out;

    float* means     = out;                           // [NVB_*5]
    float* cnts      = out + (size_t)NVB_ * 5;        // [NVB_]
    float* shape_out = out + (size_t)NVB_ * 6;        // [3]

    const size_t head_bytes = (size_t)NVB_ * 4;       // 37.3 MB
    const size_t node_bytes = (size_t)BN_ * 32;       // 38.4 MB
    const size_t need = head_bytes + node_bytes;      // ~75.7 MB

    if (ws_size >= need) {
        int*   head  = (int*)d_ws;
        float* nodes = (float*)((char*)d_ws + head_bytes);

        // heads -> -1 (0xFF bytes). ws is re-poisoned to 0xAA each launch,
        // so this must run every call.
        hipMemsetAsync(head, 0xFF, head_bytes, stream);

        voxel_build<<<(BN_ + 255) / 256, 256, 0, stream>>>(points, head, nodes);
        voxel_output<<<(NVB_ + 255) / 256, 256, 0, stream>>>(head, nodes, means, cnts, shape_out);
    } else {
        // fallback: R4 atomic-scatter path (known good)
        hipMemsetAsync(d_out, 0, (size_t)out_size * sizeof(float), stream);
        voxel_scatter<<<(BN_ + 255) / 256, 256, 0, stream>>>(points, means, cnts);
        voxel_finalize<<<(NVB_ + 255) / 256, 256, 0, stream>>>(means, cnts, shape_out);
    }
}